// Round 4
// baseline (819.112 us; speedup 1.0000x reference)
//
#include <hip/hip_runtime.h>
#include <math.h>

// Problem constants: B=256, LMAX=512, NCOND=300, NHID=600
#define BB     256
#define LMAX   512
#define NCOND  300
#define NHID   600
#define NSEG   8          // 8 segments of 64 tokens; block = one (batch, segment)
#define CHUNK  64
#define KPAD   320        // K padded to 10 chunks of 32 (k>=300 zeros in LDS/W1T)
#define NKC    10         // KPAD/32

typedef short s16x8 __attribute__((ext_vector_type(8)));  // MFMA A/B frag (8 bf16)
typedef float f32x4 __attribute__((ext_vector_type(4)));  // MFMA accumulator
typedef unsigned short u16x8 __attribute__((ext_vector_type(8)));

// fp32 -> bf16 round-to-nearest-even
__device__ inline unsigned short f2bf(float f) {
    unsigned int x = __float_as_uint(f);
    x += 0x7fffu + ((x >> 16) & 1u);
    return (unsigned short)(x >> 16);
}

// ---------------------------------------------------------------------------
// k0: build W1T bf16 in FRAGMENT-MAJOR layout:
//   w1t[((ntile*NKC + kc)*64 + lane)*8 + j] = W1[kc*32+(lane>>4)*8+j][ntile*16+(lane&15)]
// -> a wave's B-frag load is one contiguous 1 KB global_load_dwordx4.
// ---------------------------------------------------------------------------
__global__ __launch_bounds__(256) void k0_w1t(const float* __restrict__ W1,
                                              unsigned short* __restrict__ w1t)
{
    const int t     = blockIdx.x * 256 + threadIdx.x;  // 0..25599
    const int lane  = t & 63;
    const int g     = t >> 6;                          // ntile*NKC + kc
    const int ntile = g / NKC;
    const int kc    = g - ntile * NKC;
    const int n     = ntile * 16 + (lane & 15);
    const int kbase = kc * 32 + (lane >> 4) * 8;
    union { unsigned short us[8]; s16x8 v8; } u;
#pragma unroll
    for (int j = 0; j < 8; ++j) {
        const int k = kbase + j;
        const float w = (n < NHID && k < NCOND) ? W1[(size_t)k * NHID + n] : 0.f;
        u.us[j] = f2bf(w);
    }
    *(s16x8*)(w1t + (size_t)t * 8) = u.v8;
}

// ---------------------------------------------------------------------------
// k1_fused: grid (BB, NSEG), 512 threads = 8 waves. One 64-row segment per
//   block, ALL 600 cols (no ch split -> ctx read ONCE; wave wv owns n-tiles
//   [5wv,5wv+5) x 4 m-tiles). Staging converts fp32->bf16 in-kernel and
//   ds_writes to the XOR-swizzled layout (T2; read side identical to the
//   round-2/3-verified formulas). k0b is deleted: no ctx16 round trip.
//   LDS = 40,960 B exactly -> up to 4 blocks/CU (163,840 B), 24-32 waves/CU;
//   latency hiding comes from TLP (rounds 1/3 proved hand-pipelines and
//   persistence don't work here).
//   Dead segments (s*64 >= count) exit immediately -> uniform live blocks.
// ---------------------------------------------------------------------------
__global__ __launch_bounds__(512, 8) void k1_fused(
    const float* __restrict__ ctx, const int* __restrict__ lengths,
    const unsigned short* __restrict__ w1t, const float* __restrict__ b1,
    float* __restrict__ partial)
{
    const int b = blockIdx.x;
    const int s = blockIdx.y;

    int count = lengths[b]; if (count < 1) count = 1;   // reference clamps lens >= 1
    const int l0 = s * CHUNK;
    if (l0 >= count) return;                            // dead segment: no work, no write
    const int valid = min(count - l0, CHUNK);

    const int tid  = threadIdx.x;
    const int lane = tid & 63;
    const int wv   = tid >> 6;          // 0..7: wave owns n-tiles [wv*5, wv*5+5)
    const int ln15 = lane & 15;
    const int kg   = lane >> 4;

    __shared__ __align__(16) unsigned short atile[CHUNK * KPAD];   // 40,960 B exactly

    // ---- stage 64 x KPAD bf16, swizzled: off' = (row*640 + kbyte) ^ ((row&7)<<4).
    //      2560 16B-chunks / 512 threads = 5 iters exact. Rows are branchless
    //      (rows >= valid hold real ctx values, masked in epilogue); k >= 300
    //      zero-filled via the c8 guards.
    char* lds = (char*)atile;
#pragma unroll
    for (int p = 0; p < 5; ++p) {
        const int i   = p * 512 + tid;      // 0..2559
        const int row = i / 40;             // 0..63
        const int c8  = i - row * 40;       // 0..39 (8-elem group; k = c8*8)
        const float* rsrc = ctx + ((size_t)b * LMAX + l0 + row) * NCOND + c8 * 8;
        float4 v0 = make_float4(0.f, 0.f, 0.f, 0.f);
        float4 v1 = make_float4(0.f, 0.f, 0.f, 0.f);
        if (c8 < 38) v0 = *(const float4*)rsrc;          // k..k+3 <= 299
        if (c8 < 37) v1 = *(const float4*)(rsrc + 4);    // k+4..k+7 <= 299
        union { unsigned short us[8]; u16x8 v8; } o;
        o.us[0] = f2bf(v0.x); o.us[1] = f2bf(v0.y);
        o.us[2] = f2bf(v0.z); o.us[3] = f2bf(v0.w);
        o.us[4] = f2bf(v1.x); o.us[5] = f2bf(v1.y);
        o.us[6] = f2bf(v1.z); o.us[7] = f2bf(v1.w);
        const int off = (row * 640 + c8 * 16) ^ ((row & 7) << 4);   // flips bits 4-6 only
        *(u16x8*)(lds + off) = o.v8;
    }
    __syncthreads();

    // ---- MFMA: A-frag byte addr = (row*640 + kg*16 + kc*64 + mt*10240) ^ swz
    //      (identical to the round-2/3-verified read path)
    const unsigned short* bbase = w1t + ((size_t)(wv * 5) * NKC * 64 + lane) * 8;
    const int swz   = (ln15 & 7) << 4;
    const int abase = ln15 * 640 + kg * 16;
    const char* ab  = (const char*)atile;

    f32x4 acc[5][4];
#pragma unroll
    for (int nt = 0; nt < 5; ++nt)
#pragma unroll
        for (int mt = 0; mt < 4; ++mt) acc[nt][mt] = (f32x4){0.f, 0.f, 0.f, 0.f};

    s16x8 bf[2][5];
#pragma unroll
    for (int nt = 0; nt < 5; ++nt) bf[0][nt] = *(const s16x8*)(bbase + nt * 5120);

#pragma unroll
    for (int kc = 0; kc < NKC; ++kc) {
        const int cur = kc & 1, nxt = cur ^ 1;
        if (kc < NKC - 1) {
#pragma unroll
            for (int nt = 0; nt < 5; ++nt)
                bf[nxt][nt] = *(const s16x8*)(bbase + nt * 5120 + (kc + 1) * 512);
        }
        s16x8 af[4];
#pragma unroll
        for (int mt = 0; mt < 4; ++mt)
            af[mt] = *(const s16x8*)(ab + ((abase + mt * 10240 + kc * 64) ^ swz));
#pragma unroll
        for (int nt = 0; nt < 5; ++nt)
#pragma unroll
            for (int mt = 0; mt < 4; ++mt)
                acc[nt][mt] = __builtin_amdgcn_mfma_f32_16x16x32_bf16(
                    af[mt], bf[cur][nt], acc[nt][mt], 0, 0, 0);
    }

    // ---- epilogue: bias + ReLU, mask rows >= valid, reduce k-groups, write
#pragma unroll
    for (int nt = 0; nt < 5; ++nt) {
        const int colg = wv * 80 + nt * 16 + ln15;      // 0..639
        const float b1c = (colg < NHID) ? b1[colg] : 0.f;
        float ssum = 0.f;
#pragma unroll
        for (int mt = 0; mt < 4; ++mt) {
            const int rbase = mt * 16 + kg * 4;
#pragma unroll
            for (int r = 0; r < 4; ++r) {
                const float h = fmaxf(acc[nt][mt][r] + b1c, 0.f);
                if (rbase + r < valid) ssum += h;
            }
        }
        ssum += __shfl_xor(ssum, 16, 64);
        ssum += __shfl_xor(ssum, 32, 64);
        if (kg == 0 && colg < NHID)
            partial[((size_t)s * BB + b) * NHID + colg] = ssum;
    }
}

// ---------------------------------------------------------------------------
// k2: 2 batches per block (same-n lanes share Wa loads). Reduce partials over
//     sp < ceil(len/64) (others unwritten/poisoned -> skipped), /len, then
//     gate = sigmoid(pooled@Wa + ba); out = gate * x.   (round-0 proven)
// NOTE: NHID/4 = 150 float4s = 37*4 + 2 -> 4-wide main loop to h4<148, then
//       a 2-float4 tail.
// ---------------------------------------------------------------------------
__global__ __launch_bounds__(640) void k2_gate(
    const float* __restrict__ x, const int* __restrict__ lengths,
    const float* __restrict__ partial, const float* __restrict__ Wa,
    const float* __restrict__ ba, float* __restrict__ out)
{
    const int b0  = blockIdx.x * 2;
    const int tid = threadIdx.x;

    __shared__ float pl[2][NHID];

    if (tid < NHID) {
#pragma unroll
        for (int bb = 0; bb < 2; ++bb) {
            int count = lengths[b0 + bb]; if (count < 1) count = 1;
            const int nch = (count + CHUNK - 1) >> 6;
            float ssum = 0.f;
            for (int sp = 0; sp < nch; ++sp)
                ssum += partial[((size_t)sp * BB + (b0 + bb)) * NHID + tid];
            pl[bb][tid] = ssum / (float)count;
        }
    }
    __syncthreads();

    if (tid < 2 * NCOND) {
        const int bb = tid / NCOND;        // 0 or 1
        const int n  = tid - bb * NCOND;   // lanes 0..299 and 300..599 share Wa addrs
        const int b  = b0 + bb;
        float a0 = ba[n], a1 = 0.f, a2 = 0.f, a3 = 0.f;
        const float4* p4 = (const float4*)pl[bb];
        for (int h4 = 0; h4 < 148; h4 += 4) {   // h = 0..591
            const float4 pv0 = p4[h4];
            const float4 pv1 = p4[h4 + 1];
            const float4 pv2 = p4[h4 + 2];
            const float4 pv3 = p4[h4 + 3];
            const int hb = h4 * 4;
            a0 = fmaf(pv0.x, Wa[(size_t)(hb +  0) * NCOND + n], a0);
            a0 = fmaf(pv0.y, Wa[(size_t)(hb +  1) * NCOND + n], a0);
            a0 = fmaf(pv0.z, Wa[(size_t)(hb +  2) * NCOND + n], a0);
            a0 = fmaf(pv0.w, Wa[(size_t)(hb +  3) * NCOND + n], a0);
            a1 = fmaf(pv1.x, Wa[(size_t)(hb +  4) * NCOND + n], a1);
            a1 = fmaf(pv1.y, Wa[(size_t)(hb +  5) * NCOND + n], a1);
            a1 = fmaf(pv1.z, Wa[(size_t)(hb +  6) * NCOND + n], a1);
            a1 = fmaf(pv1.w, Wa[(size_t)(hb +  7) * NCOND + n], a1);
            a2 = fmaf(pv2.x, Wa[(size_t)(hb +  8) * NCOND + n], a2);
            a2 = fmaf(pv2.y, Wa[(size_t)(hb +  9) * NCOND + n], a2);
            a2 = fmaf(pv2.z, Wa[(size_t)(hb + 10) * NCOND + n], a2);
            a2 = fmaf(pv2.w, Wa[(size_t)(hb + 11) * NCOND + n], a2);
            a3 = fmaf(pv3.x, Wa[(size_t)(hb + 12) * NCOND + n], a3);
            a3 = fmaf(pv3.y, Wa[(size_t)(hb + 13) * NCOND + n], a3);
            a3 = fmaf(pv3.z, Wa[(size_t)(hb + 14) * NCOND + n], a3);
            a3 = fmaf(pv3.w, Wa[(size_t)(hb + 15) * NCOND + n], a3);
        }
        {   // tail: h = 592..599
            const float4 pv0 = p4[148];
            const float4 pv1 = p4[149];
            a0 = fmaf(pv0.x, Wa[(size_t)592 * NCOND + n], a0);
            a0 = fmaf(pv0.y, Wa[(size_t)593 * NCOND + n], a0);
            a0 = fmaf(pv0.z, Wa[(size_t)594 * NCOND + n], a0);
            a0 = fmaf(pv0.w, Wa[(size_t)595 * NCOND + n], a0);
            a1 = fmaf(pv1.x, Wa[(size_t)596 * NCOND + n], a1);
            a1 = fmaf(pv1.y, Wa[(size_t)597 * NCOND + n], a1);
            a1 = fmaf(pv1.z, Wa[(size_t)598 * NCOND + n], a1);
            a1 = fmaf(pv1.w, Wa[(size_t)599 * NCOND + n], a1);
        }
        const float acc  = (a0 + a1) + (a2 + a3);
        const float gate = 1.0f / (1.0f + expf(-acc));
        out[(size_t)b * NCOND + n] = gate * x[(size_t)b * NCOND + n];
    }
}

extern "C" void kernel_launch(void* const* d_in, const int* in_sizes, int n_in,
                              void* d_out, int out_size, void* d_ws, size_t ws_size,
                              hipStream_t stream)
{
    // setup_inputs() order: x, context, lengths, W1, b1, Wa, ba
    const float* x       = (const float*)d_in[0];
    const float* ctx     = (const float*)d_in[1];
    const int*   lengths = (const int*)  d_in[2];
    const float* W1      = (const float*)d_in[3];
    const float* b1      = (const float*)d_in[4];
    const float* Wa      = (const float*)d_in[5];
    const float* ba      = (const float*)d_in[6];
    float*       out     = (float*)d_out;

    // ws layout: [w1t frag-major bf16: 409,600 B][partial fp32 8*256*600: 4,915,200 B]
    unsigned short* w1t     = (unsigned short*)d_ws;
    float*          partial = (float*)((char*)d_ws + 409600);

    k0_w1t<<<100, 256, 0, stream>>>(W1, w1t);
    k1_fused<<<dim3(BB, NSEG), 512, 0, stream>>>(ctx, lengths, w1t, b1, partial);
    k2_gate<<<BB / 2, 640, 0, stream>>>(x, lengths, partial, Wa, ba, out);
}

// Round 6
// 368.460 us; speedup vs baseline: 2.2231x; 2.2231x over previous
//
#include <hip/hip_runtime.h>
#include <math.h>

// Problem constants: B=256, LMAX=512, NCOND=300, NHID=600
#define BB     256
#define LMAX   512
#define NCOND  300
#define NHID   600
#define NSEG   8          // 8 segments of 64 tokens; block = one (batch, segment, colhalf)
#define CHUNK  64
#define KPAD   320        // K padded to 10 chunks of 32 (k>=300 REAL zeros in ctx16/W1T)
#define KLDS   328        // fallback-path LDS row stride
#define NKC    10         // KPAD/32
#define TILE16 20480      // u16 elems per fragment-major ctx16 tile (64*320)

typedef short s16x8 __attribute__((ext_vector_type(8)));  // MFMA A/B frag (8 bf16)
typedef float f32x4 __attribute__((ext_vector_type(4)));  // MFMA accumulator
typedef unsigned short u16x8 __attribute__((ext_vector_type(8)));

// fp32 -> bf16 round-to-nearest-even (bit-exact with all passing rounds)
__device__ inline unsigned short f2bf(float f) {
    unsigned int x = __float_as_uint(f);
    x += 0x7fffu + ((x >> 16) & 1u);
    return (unsigned short)(x >> 16);
}

// ---------------------------------------------------------------------------
// k0: build W1T bf16 in FRAGMENT-MAJOR layout:
//   w1t[((ntile*NKC + kc)*64 + lane)*8 + j] = W1[kc*32+(lane>>4)*8+j][ntile*16+(lane&15)]
// -> a wave's B-frag load is one contiguous 1 KB global_load_dwordx4.
// ---------------------------------------------------------------------------
__global__ __launch_bounds__(256) void k0_w1t(const float* __restrict__ W1,
                                              unsigned short* __restrict__ w1t)
{
    const int t     = blockIdx.x * 256 + threadIdx.x;  // 0..25599
    const int lane  = t & 63;
    const int g     = t >> 6;                          // ntile*NKC + kc
    const int ntile = g / NKC;
    const int kc    = g - ntile * NKC;
    const int n     = ntile * 16 + (lane & 15);
    const int kbase = kc * 32 + (lane >> 4) * 8;
    union { unsigned short us[8]; s16x8 v8; } u;
#pragma unroll
    for (int j = 0; j < 8; ++j) {
        const int k = kbase + j;
        const float w = (n < NHID && k < NCOND) ? W1[(size_t)k * NHID + n] : 0.f;
        u.us[j] = f2bf(w);
    }
    *(s16x8*)(w1t + (size_t)t * 8) = u.v8;
}

// ---------------------------------------------------------------------------
// k0b_frag: pre-convert ctx (fp32) -> ctx16 (bf16) in FRAGMENT-MAJOR layout,
//   live segments only. Per 64-row tile (b,s):
//     elem (row, k=8q+j) -> ctx16[tile*TILE16 + ((mt*NKC+kc)*64 + lane)*8 + j]
//     with mt=row>>4, kc=q>>2, lane=(q&3)*16 + (row&15)
//   so a k1 wave's A-frag load for (mt,kc) is ONE contiguous 1 KB chunk --
//   identical addressing to w1t (the proven-fast B path). k >= 300 REAL zeros.
//   Reads are row-linear coalesced; scattered 16B writes absorbed by L2.
// ---------------------------------------------------------------------------
__global__ __launch_bounds__(256) void k0b_frag(const float* __restrict__ ctx,
                                                const int* __restrict__ lengths,
                                                unsigned short* __restrict__ ctx16)
{
    const int b = blockIdx.x, s = blockIdx.y, tid = threadIdx.x;
    int count = lengths[b]; if (count < 1) count = 1;
    if (s * CHUNK >= count) return;                    // dead tile: k1 never reads it

    const float* src = ctx + ((size_t)b * LMAX + s * CHUNK) * NCOND;
    unsigned short* dst = ctx16 + (size_t)(b * NSEG + s) * TILE16;

#pragma unroll
    for (int p = 0; p < 10; ++p) {
        const int i   = p * 256 + tid;      // 0..2559 (16B chunk index)
        const int row = i / 40;             // 0..63
        const int q   = i - row * 40;       // 0..39 (8-elem k-group; k = 8q)
        float4 v0 = make_float4(0.f, 0.f, 0.f, 0.f);
        float4 v1 = make_float4(0.f, 0.f, 0.f, 0.f);
        const float* rsrc = src + (size_t)row * NCOND + q * 8;
        if (q < 38) v0 = *(const float4*)rsrc;          // k..k+3   <= 299
        if (q < 37) v1 = *(const float4*)(rsrc + 4);    // k+4..k+7 <= 299
        union { unsigned short us[8]; u16x8 v8; } o;
        o.us[0] = f2bf(v0.x); o.us[1] = f2bf(v0.y);
        o.us[2] = f2bf(v0.z); o.us[3] = f2bf(v0.w);
        o.us[4] = f2bf(v1.x); o.us[5] = f2bf(v1.y);
        o.us[6] = f2bf(v1.z); o.us[7] = f2bf(v1.w);
        const int mt = row >> 4, kc = q >> 2;
        const int lane = ((q & 3) << 4) + (row & 15);
        *(u16x8*)(dst + (((mt * NKC + kc) * 64 + lane) << 3)) = o.v8;
    }
}

// ---------------------------------------------------------------------------
// k1_direct: grid (2, NSEG, BB) -- ch FASTEST so the two blocks sharing an
//   A-tile are dispatch-adjacent (same XCD -> L2 hit). 256 threads = 4 waves.
//   NO LDS, NO barriers, NO conversion: per kc the wave issues 4 A-loads +
//   5 B-loads (each one contiguous 1 KB, ping-pong prefetched one kc ahead)
//   and 20 MFMAs. Pure independent streams; latency hidden by lookahead +
//   2 waves/SIMD, not barrier-phased staging (rounds 0-4 evidence).
// ---------------------------------------------------------------------------
__global__ __launch_bounds__(256, 2) void k1_direct(
    const unsigned short* __restrict__ ctx16, const int* __restrict__ lengths,
    const unsigned short* __restrict__ w1t, const float* __restrict__ b1,
    float* __restrict__ partial)
{
    const int ch = blockIdx.x;
    const int s  = blockIdx.y;
    const int b  = blockIdx.z;

    int count = lengths[b]; if (count < 1) count = 1;   // reference clamps lens >= 1
    const int l0 = s * CHUNK;
    if (l0 >= count) return;                            // dead segment: no work, no write
    const int valid = min(count - l0, CHUNK);

    const int tid  = threadIdx.x;
    const int lane = tid & 63;
    const int wv   = tid >> 6;          // 0..3: wave owns n-tiles ch*20 + [wv*5, wv*5+5)
    const int ln15 = lane & 15;
    const int kg   = lane >> 4;

    // per-lane fragment bases; frag (mt|nt, kc) at +mt*5120 + kc*512 elems
    const unsigned short* abase = ctx16 + (size_t)(b * NSEG + s) * TILE16 + (size_t)lane * 8;
    const unsigned short* bbase = w1t + ((size_t)(ch * 20 + wv * 5) * NKC * 64 + lane) * 8;

    f32x4 acc[5][4];
#pragma unroll
    for (int nt = 0; nt < 5; ++nt)
#pragma unroll
        for (int mt = 0; mt < 4; ++mt) acc[nt][mt] = (f32x4){0.f, 0.f, 0.f, 0.f};

    s16x8 af[2][4], bf[2][5];
#pragma unroll
    for (int mt = 0; mt < 4; ++mt) af[0][mt] = *(const s16x8*)(abase + mt * 5120);
#pragma unroll
    for (int nt = 0; nt < 5; ++nt) bf[0][nt] = *(const s16x8*)(bbase + nt * 5120);

#pragma unroll
    for (int kc = 0; kc < NKC; ++kc) {
        const int cur = kc & 1, nxt = cur ^ 1;
        if (kc < NKC - 1) {
#pragma unroll
            for (int mt = 0; mt < 4; ++mt)
                af[nxt][mt] = *(const s16x8*)(abase + mt * 5120 + (kc + 1) * 512);
#pragma unroll
            for (int nt = 0; nt < 5; ++nt)
                bf[nxt][nt] = *(const s16x8*)(bbase + nt * 5120 + (kc + 1) * 512);
        }
#pragma unroll
        for (int nt = 0; nt < 5; ++nt)
#pragma unroll
            for (int mt = 0; mt < 4; ++mt)
                acc[nt][mt] = __builtin_amdgcn_mfma_f32_16x16x32_bf16(
                    af[cur][mt], bf[cur][nt], acc[nt][mt], 0, 0, 0);
    }

    // ---- epilogue: bias + ReLU, mask rows >= valid, reduce k-groups, write
#pragma unroll
    for (int nt = 0; nt < 5; ++nt) {
        const int colg = ch * 320 + wv * 80 + nt * 16 + ln15;
        const float b1c = (colg < NHID) ? b1[colg] : 0.f;
        float ssum = 0.f;
#pragma unroll
        for (int mt = 0; mt < 4; ++mt) {
            const int rbase = mt * 16 + kg * 4;
#pragma unroll
            for (int r = 0; r < 4; ++r) {
                const float h = fmaxf(acc[nt][mt][r] + b1c, 0.f);
                if (rbase + r < valid) ssum += h;
            }
        }
        ssum += __shfl_xor(ssum, 16, 64);
        ssum += __shfl_xor(ssum, 32, 64);
        if (kg == 0 && colg < NHID)
            partial[((size_t)s * BB + b) * NHID + colg] = ssum;
    }
}

// ---------------------------------------------------------------------------
// k2: 2 batches per block (same-n lanes share Wa loads). Reduce partials over
//     sp < ceil(len/64) (others unwritten/poisoned -> skipped), /len, then
//     gate = sigmoid(pooled@Wa + ba); out = gate * x.   (round-0 proven)
// ---------------------------------------------------------------------------
__global__ __launch_bounds__(640) void k2_gate(
    const float* __restrict__ x, const int* __restrict__ lengths,
    const float* __restrict__ partial, const float* __restrict__ Wa,
    const float* __restrict__ ba, float* __restrict__ out)
{
    const int b0  = blockIdx.x * 2;
    const int tid = threadIdx.x;

    __shared__ float pl[2][NHID];

    if (tid < NHID) {
#pragma unroll
        for (int bb = 0; bb < 2; ++bb) {
            int count = lengths[b0 + bb]; if (count < 1) count = 1;
            const int nch = (count + CHUNK - 1) >> 6;
            float ssum = 0.f;
            for (int sp = 0; sp < nch; ++sp)
                ssum += partial[((size_t)sp * BB + (b0 + bb)) * NHID + tid];
            pl[bb][tid] = ssum / (float)count;
        }
    }
    __syncthreads();

    if (tid < 2 * NCOND) {
        const int bb = tid / NCOND;        // 0 or 1
        const int n  = tid - bb * NCOND;   // lanes 0..299 and 300..599 share Wa addrs
        const int b  = b0 + bb;
        float a0 = ba[n], a1 = 0.f, a2 = 0.f, a3 = 0.f;
        const float4* p4 = (const float4*)pl[bb];
        for (int h4 = 0; h4 < 148; h4 += 4) {   // h = 0..591
            const float4 pv0 = p4[h4];
            const float4 pv1 = p4[h4 + 1];
            const float4 pv2 = p4[h4 + 2];
            const float4 pv3 = p4[h4 + 3];
            const int hb = h4 * 4;
            a0 = fmaf(pv0.x, Wa[(size_t)(hb +  0) * NCOND + n], a0);
            a0 = fmaf(pv0.y, Wa[(size_t)(hb +  1) * NCOND + n], a0);
            a0 = fmaf(pv0.z, Wa[(size_t)(hb +  2) * NCOND + n], a0);
            a0 = fmaf(pv0.w, Wa[(size_t)(hb +  3) * NCOND + n], a0);
            a1 = fmaf(pv1.x, Wa[(size_t)(hb +  4) * NCOND + n], a1);
            a1 = fmaf(pv1.y, Wa[(size_t)(hb +  5) * NCOND + n], a1);
            a1 = fmaf(pv1.z, Wa[(size_t)(hb +  6) * NCOND + n], a1);
            a1 = fmaf(pv1.w, Wa[(size_t)(hb +  7) * NCOND + n], a1);
            a2 = fmaf(pv2.x, Wa[(size_t)(hb +  8) * NCOND + n], a2);
            a2 = fmaf(pv2.y, Wa[(size_t)(hb +  9) * NCOND + n], a2);
            a2 = fmaf(pv2.z, Wa[(size_t)(hb + 10) * NCOND + n], a2);
            a2 = fmaf(pv2.w, Wa[(size_t)(hb + 11) * NCOND + n], a2);
            a3 = fmaf(pv3.x, Wa[(size_t)(hb + 12) * NCOND + n], a3);
            a3 = fmaf(pv3.y, Wa[(size_t)(hb + 13) * NCOND + n], a3);
            a3 = fmaf(pv3.z, Wa[(size_t)(hb + 14) * NCOND + n], a3);
            a3 = fmaf(pv3.w, Wa[(size_t)(hb + 15) * NCOND + n], a3);
        }
        {   // tail: h = 592..599
            const float4 pv0 = p4[148];
            const float4 pv1 = p4[149];
            a0 = fmaf(pv0.x, Wa[(size_t)592 * NCOND + n], a0);
            a0 = fmaf(pv0.y, Wa[(size_t)593 * NCOND + n], a0);
            a0 = fmaf(pv0.z, Wa[(size_t)594 * NCOND + n], a0);
            a0 = fmaf(pv0.w, Wa[(size_t)595 * NCOND + n], a0);
            a1 = fmaf(pv1.x, Wa[(size_t)596 * NCOND + n], a1);
            a1 = fmaf(pv1.y, Wa[(size_t)597 * NCOND + n], a1);
            a1 = fmaf(pv1.z, Wa[(size_t)598 * NCOND + n], a1);
            a1 = fmaf(pv1.w, Wa[(size_t)599 * NCOND + n], a1);
        }
        const float acc  = (a0 + a1) + (a2 + a3);
        const float gate = 1.0f / (1.0f + expf(-acc));
        out[(size_t)b * NCOND + n] = gate * x[(size_t)b * NCOND + n];
    }
}

// ---------------------------------------------------------------------------
// Fallback path (ws too small for ctx16): exact round-0 kernel.
// ---------------------------------------------------------------------------
__global__ __launch_bounds__(256, 3) void k1_mfma_pool(
    const float* __restrict__ ctx, const int* __restrict__ lengths,
    const unsigned short* __restrict__ w1t, const float* __restrict__ b1,
    float* __restrict__ partial)
{
    const int b  = blockIdx.x;
    const int s  = blockIdx.y;
    const int ch = blockIdx.z;

    int count = lengths[b]; if (count < 1) count = 1;
    const int l0 = s * CHUNK;
    if (l0 >= count) return;
    const int valid = min(count - l0, CHUNK);

    const int tid  = threadIdx.x;
    const int lane = tid & 63;
    const int wv   = tid >> 6;
    const int ln15 = lane & 15;
    const int kg   = lane >> 4;

    __shared__ __align__(16) unsigned short atile[CHUNK * KLDS];

#pragma unroll
    for (int p = 0; p < 10; ++p) {
        const int i  = p * 256 + tid;
        const int r  = i / 40;
        const int c8 = i - r * 40;
        union { unsigned short us[8]; s16x8 v8; } u;
        if (r < valid && c8 < 38) {
            const float* src = ctx + ((size_t)b * LMAX + l0 + r) * NCOND + c8 * 8;
            const float4 v0 = *(const float4*)src;
            float4 v1 = make_float4(0.f, 0.f, 0.f, 0.f);
            if (c8 < 37) v1 = *(const float4*)(src + 4);
            u.us[0] = f2bf(v0.x); u.us[1] = f2bf(v0.y);
            u.us[2] = f2bf(v0.z); u.us[3] = f2bf(v0.w);
            u.us[4] = f2bf(v1.x); u.us[5] = f2bf(v1.y);
            u.us[6] = f2bf(v1.z); u.us[7] = f2bf(v1.w);
        } else {
#pragma unroll
            for (int j = 0; j < 8; ++j) u.us[j] = 0;
        }
        *(s16x8*)(atile + r * KLDS + c8 * 8) = u.v8;
    }
    __syncthreads();

    const int ntile0 = ch * 20 + wv * 5;
    const unsigned short* bbase = w1t + ((size_t)ntile0 * NKC * 64 + lane) * 8;
    const unsigned short* arow  = atile + ln15 * KLDS + kg * 8;

    f32x4 acc[5][4];
#pragma unroll
    for (int nt = 0; nt < 5; ++nt)
#pragma unroll
        for (int mt = 0; mt < 4; ++mt) acc[nt][mt] = (f32x4){0.f, 0.f, 0.f, 0.f};

    s16x8 bf[2][5];
#pragma unroll
    for (int nt = 0; nt < 5; ++nt) bf[0][nt] = *(const s16x8*)(bbase + nt * 5120);

#pragma unroll
    for (int kc = 0; kc < NKC; ++kc) {
        const int cur = kc & 1, nxt = cur ^ 1;
        if (kc < NKC - 1) {
#pragma unroll
            for (int nt = 0; nt < 5; ++nt)
                bf[nxt][nt] = *(const s16x8*)(bbase + nt * 5120 + (kc + 1) * 512);
        }
        s16x8 af[4];
#pragma unroll
        for (int mt = 0; mt < 4; ++mt)
            af[mt] = *(const s16x8*)(arow + mt * 16 * KLDS + kc * 32);
#pragma unroll
        for (int nt = 0; nt < 5; ++nt)
#pragma unroll
            for (int mt = 0; mt < 4; ++mt)
                acc[nt][mt] = __builtin_amdgcn_mfma_f32_16x16x32_bf16(
                    af[mt], bf[cur][nt], acc[nt][mt], 0, 0, 0);
    }

#pragma unroll
    for (int nt = 0; nt < 5; ++nt) {
        const int colg = ch * 320 + wv * 80 + nt * 16 + ln15;
        const float b1c = (colg < NHID) ? b1[colg] : 0.f;
        float ssum = 0.f;
#pragma unroll
        for (int mt = 0; mt < 4; ++mt) {
            const int rbase = mt * 16 + kg * 4;
#pragma unroll
            for (int r = 0; r < 4; ++r) {
                const float h = fmaxf(acc[nt][mt][r] + b1c, 0.f);
                if (rbase + r < valid) ssum += h;
            }
        }
        ssum += __shfl_xor(ssum, 16, 64);
        ssum += __shfl_xor(ssum, 32, 64);
        if (kg == 0 && colg < NHID)
            partial[((size_t)s * BB + b) * NHID + colg] = ssum;
    }
}

extern "C" void kernel_launch(void* const* d_in, const int* in_sizes, int n_in,
                              void* d_out, int out_size, void* d_ws, size_t ws_size,
                              hipStream_t stream)
{
    // setup_inputs() order: x, context, lengths, W1, b1, Wa, ba
    const float* x       = (const float*)d_in[0];
    const float* ctx     = (const float*)d_in[1];
    const int*   lengths = (const int*)  d_in[2];
    const float* W1      = (const float*)d_in[3];
    const float* b1      = (const float*)d_in[4];
    const float* Wa      = (const float*)d_in[5];
    const float* ba      = (const float*)d_in[6];
    float*       out     = (float*)d_out;

    // ws layout: [w1t 409,600][partial 4,915,200][ctx16 frag-major 83,886,080]
    const size_t W1T_B   = 409600;
    const size_t PART_B  = 4915200;                         // [8][256][600] f32
    const size_t CTX16_B = (size_t)BB * NSEG * TILE16 * 2;  // 83,886,080
    const size_t NEED    = W1T_B + PART_B + CTX16_B;

    unsigned short* w1t     = (unsigned short*)d_ws;
    float*          partial = (float*)((char*)d_ws + W1T_B);

    k0_w1t<<<100, 256, 0, stream>>>(W1, w1t);

    if (ws_size >= NEED) {
        unsigned short* ctx16 = (unsigned short*)((char*)d_ws + W1T_B + PART_B);
        k0b_frag<<<dim3(BB, NSEG), 256, 0, stream>>>(ctx, lengths, ctx16);
        k1_direct<<<dim3(2, NSEG, BB), 256, 0, stream>>>(ctx16, lengths, w1t, b1, partial);
    } else {
        k1_mfma_pool<<<dim3(BB, NSEG, 2), 256, 0, stream>>>(ctx, lengths, w1t, b1, partial);
    }

    k2_gate<<<BB / 2, 640, 0, stream>>>(x, lengths, partial, Wa, ba, out);
}

// Round 7
// 323.842 us; speedup vs baseline: 2.5294x; 1.1378x over previous
//
#include <hip/hip_runtime.h>
#include <math.h>

// Problem constants: B=256, LMAX=512, NCOND=300, NHID=600
#define BB     256
#define LMAX   512
#define NCOND  300
#define NHID   600
#define NSEG   8          // 8 segments of 64 tokens
#define CHUNK  64
#define KPAD   320        // K padded to 10 chunks of 32 (k>=300 REAL zeros in ctx16/W1T)
#define KLDS   328        // fallback-path LDS row stride
#define NKC    10         // KPAD/32

#define AS1 __attribute__((address_space(1)))
#define AS3 __attribute__((address_space(3)))

typedef short s16x8 __attribute__((ext_vector_type(8)));  // MFMA A/B frag (8 bf16)
typedef float f32x4 __attribute__((ext_vector_type(4)));  // MFMA accumulator
typedef unsigned short u16x8 __attribute__((ext_vector_type(8)));

// fp32 -> bf16 round-to-nearest-even (bit-exact with all passing rounds)
__device__ inline unsigned short f2bf(float f) {
    unsigned int x = __float_as_uint(f);
    x += 0x7fffu + ((x >> 16) & 1u);
    return (unsigned short)(x >> 16);
}

// ---------------------------------------------------------------------------
// k0: build W1T bf16 in FRAGMENT-MAJOR layout (round-0 proven):
//   w1t[((ntile*NKC + kc)*64 + lane)*8 + j] = W1[kc*32+(lane>>4)*8+j][ntile*16+(lane&15)]
// ---------------------------------------------------------------------------
__global__ __launch_bounds__(256) void k0_w1t(const float* __restrict__ W1,
                                              unsigned short* __restrict__ w1t)
{
    const int t     = blockIdx.x * 256 + threadIdx.x;  // 0..25599
    const int lane  = t & 63;
    const int g     = t >> 6;                          // ntile*NKC + kc
    const int ntile = g / NKC;
    const int kc    = g - ntile * NKC;
    const int n     = ntile * 16 + (lane & 15);
    const int kbase = kc * 32 + (lane >> 4) * 8;
    union { unsigned short us[8]; s16x8 v8; } u;
#pragma unroll
    for (int j = 0; j < 8; ++j) {
        const int k = kbase + j;
        const float w = (n < NHID && k < NCOND) ? W1[(size_t)k * NHID + n] : 0.f;
        u.us[j] = f2bf(w);
    }
    *(s16x8*)(w1t + (size_t)t * 8) = u.v8;
}

// ---------------------------------------------------------------------------
// k0b_cvt (round-3 verified): ctx fp32 -> ctx16 bf16, live segments only,
//   row layout KPAD=320 (k>=300 REAL zeros), bytes PRE-SWIZZLED within each
//   40,960 B segment:  off' = (row*640 + kbyte) ^ ((row&7)<<4)
//   so k1's LINEAR global_load_lds lands the tile swizzled in LDS (rule #21).
//   2560 16B chunks / 256 threads = 10 iters exact; writes near-linear
//   (XOR permutes bits 4-6 only).
// ---------------------------------------------------------------------------
__global__ __launch_bounds__(256) void k0b_cvt(const float* __restrict__ ctx,
                                               const int* __restrict__ lengths,
                                               unsigned short* __restrict__ ctx16)
{
    const int b = blockIdx.x, s = blockIdx.y, tid = threadIdx.x;
    int count = lengths[b]; if (count < 1) count = 1;
    if (s * CHUNK >= count) return;                    // dead segment: k1 never reads it

    const float* src = ctx + ((size_t)b * LMAX + s * CHUNK) * NCOND;
    char* dst = (char*)(ctx16 + ((size_t)b * LMAX + s * CHUNK) * KPAD);

#pragma unroll
    for (int i = 0; i < 10; ++i) {
        const int c   = i * 256 + tid;      // 0..2559 (16B output chunk index)
        const int row = c / 40;             // 0..63
        const int q2  = c - row * 40;       // 0..39 (8-elem group; k = q2*8)
        float4 v0 = make_float4(0.f, 0.f, 0.f, 0.f);
        float4 v1 = make_float4(0.f, 0.f, 0.f, 0.f);
        const float* rsrc = src + (size_t)row * NCOND + q2 * 8;
        if (q2 < 38) v0 = *(const float4*)rsrc;          // k..k+3   <= 299
        if (q2 < 37) v1 = *(const float4*)(rsrc + 4);    // k+4..k+7 <= 299
        union { unsigned short us[8]; u16x8 v8; } o;
        o.us[0] = f2bf(v0.x); o.us[1] = f2bf(v0.y);
        o.us[2] = f2bf(v0.z); o.us[3] = f2bf(v0.w);
        o.us[4] = f2bf(v1.x); o.us[5] = f2bf(v1.y);
        o.us[6] = f2bf(v1.z); o.us[7] = f2bf(v1.w);
        const int off = (row * 640 + q2 * 16) ^ ((row & 7) << 4);
        *(u16x8*)(dst + off) = o.v8;
    }
}

// ---------------------------------------------------------------------------
// k1_dma2: grid (BB, NSEG, 2) x 512 threads = 8 waves. Round-2's verified
//   DMA+XOR machinery with HALVED per-wave register footprint for occupancy:
//   wave wv: nt-group wvn=wv&3 (5 n-tiles), mt-half mh=wv>>2 (2 m-tiles).
//   acc[5][2]=40 + bf[2][5]=40 + af[2][2]=8 + addr ~25 => ~115 regs;
//   __launch_bounds__(512,4) caps at 128 -> 4 waves/SIMD, 16 waves/CU
//   (vs 12 in every previous k1). LDS 42,240 B -> 2 blocks/CU.
//   mt-halves combine via a 320-float LDS buffer + one barrier.
// ---------------------------------------------------------------------------
__global__ __launch_bounds__(512, 4) void k1_dma2(
    const unsigned short* __restrict__ ctx16, const int* __restrict__ lengths,
    const unsigned short* __restrict__ w1t, const float* __restrict__ b1,
    float* __restrict__ partial)
{
    const int b  = blockIdx.x;
    const int s  = blockIdx.y;
    const int ch = blockIdx.z;

    int count = lengths[b]; if (count < 1) count = 1;   // reference clamps lens >= 1
    const int l0 = s * CHUNK;
    if (l0 >= count) return;                            // dead segment: no work, no write
    const int valid = min(count - l0, CHUNK);

    const int tid  = threadIdx.x;
    const int lane = tid & 63;
    const int wv   = tid >> 6;          // 0..7
    const int wvn  = wv & 3;            // nt group: n-tiles ch*20 + wvn*5 + [0,5)
    const int mh   = wv >> 2;           // mt half: mt in {2mh, 2mh+1}
    const int ln15 = lane & 15;
    const int kg   = lane >> 4;

    __shared__ __align__(16) unsigned short atile[CHUNK * KPAD];  // 40,960 B
    __shared__ float red[320];                                    // +1,280 B

    // ---- stage: 5 linear DMA issues per wave (40,960 B exactly, pre-swizzled src)
    const char* gsrc = (const char*)(ctx16 + ((size_t)b * LMAX + l0) * KPAD);
    char* lbase = (char*)atile;
#pragma unroll
    for (int i = 0; i < 5; ++i) {
        const int off = (i * 8 + wv) * 1024;     // wave-uniform LDS base; HW adds lane*16
        __builtin_amdgcn_global_load_lds(
            (const AS1 void*)(gsrc + off + lane * 16),
            (AS3 void*)(lbase + off), 16, 0, 0);
    }

    // ---- prefetch kc=0 B-frags while the DMA drains (independent of LDS)
    const unsigned short* bbase = w1t + ((size_t)(ch * 20 + wvn * 5) * NKC * 64 + lane) * 8;
    s16x8 bf[2][5];
#pragma unroll
    for (int nt = 0; nt < 5; ++nt) bf[0][nt] = *(const s16x8*)(bbase + nt * 5120);

    // A-frag addressing (round-2/3 verified): byte = (row*640 + kg*16 + mt*10240
    //   + kc*64) ^ ((row&7)<<4), row = ln15
    const int swz    = (ln15 & 7) << 4;
    const int abyte0 = ln15 * 640 + kg * 16 + (mh * 2) * 10240;
    const char* ab   = (const char*)atile;

    f32x4 acc[5][2];
#pragma unroll
    for (int nt = 0; nt < 5; ++nt) {
        acc[nt][0] = (f32x4){0.f, 0.f, 0.f, 0.f};
        acc[nt][1] = (f32x4){0.f, 0.f, 0.f, 0.f};
    }

    __syncthreads();                                    // DMA drain + block sync

    s16x8 af[2][2];
    af[0][0] = *(const s16x8*)(ab + ((abyte0)         ^ swz));
    af[0][1] = *(const s16x8*)(ab + ((abyte0 + 10240) ^ swz));

#pragma unroll
    for (int kc = 0; kc < NKC; ++kc) {
        const int cur = kc & 1, nxt = cur ^ 1;
        if (kc < NKC - 1) {
            af[nxt][0] = *(const s16x8*)(ab + ((abyte0 +         (kc + 1) * 64) ^ swz));
            af[nxt][1] = *(const s16x8*)(ab + ((abyte0 + 10240 + (kc + 1) * 64) ^ swz));
#pragma unroll
            for (int nt = 0; nt < 5; ++nt)
                bf[nxt][nt] = *(const s16x8*)(bbase + nt * 5120 + (kc + 1) * 512);
        }
#pragma unroll
        for (int nt = 0; nt < 5; ++nt) {
            acc[nt][0] = __builtin_amdgcn_mfma_f32_16x16x32_bf16(
                af[cur][0], bf[cur][nt], acc[nt][0], 0, 0, 0);
            acc[nt][1] = __builtin_amdgcn_mfma_f32_16x16x32_bf16(
                af[cur][1], bf[cur][nt], acc[nt][1], 0, 0, 0);
        }
    }

    // ---- epilogue: bias + ReLU, mask rows >= valid, reduce kg, combine mt-halves
    float sfin[5];
#pragma unroll
    for (int nt = 0; nt < 5; ++nt) {
        const int colg = ch * 320 + wvn * 80 + nt * 16 + ln15;
        const float b1c = (colg < NHID) ? b1[colg] : 0.f;
        float ssum = 0.f;
#pragma unroll
        for (int j = 0; j < 2; ++j) {
            const int rbase = (mh * 2 + j) * 16 + kg * 4;
#pragma unroll
            for (int r = 0; r < 4; ++r) {
                const float h = fmaxf(acc[nt][j][r] + b1c, 0.f);
                if (rbase + r < valid) ssum += h;
            }
        }
        ssum += __shfl_xor(ssum, 16, 64);
        ssum += __shfl_xor(ssum, 32, 64);
        sfin[nt] = ssum;
    }

    if (mh == 1) {
#pragma unroll
        for (int nt = 0; nt < 5; ++nt)
            if (kg == 0) red[wvn * 80 + nt * 16 + ln15] = sfin[nt];
    }
    __syncthreads();
    if (mh == 0) {
#pragma unroll
        for (int nt = 0; nt < 5; ++nt) {
            const int colg = ch * 320 + wvn * 80 + nt * 16 + ln15;
            const float v = sfin[nt] + red[wvn * 80 + nt * 16 + ln15];
            if (kg == 0 && colg < NHID)
                partial[((size_t)s * BB + b) * NHID + colg] = v;
        }
    }
}

// ---------------------------------------------------------------------------
// k2: 2 batches per block (same-n lanes share Wa loads). Reduce partials over
//     sp < ceil(len/64) (others unwritten/poisoned -> skipped), /len, then
//     gate = sigmoid(pooled@Wa + ba); out = gate * x.   (round-0 proven)
// ---------------------------------------------------------------------------
__global__ __launch_bounds__(640) void k2_gate(
    const float* __restrict__ x, const int* __restrict__ lengths,
    const float* __restrict__ partial, const float* __restrict__ Wa,
    const float* __restrict__ ba, float* __restrict__ out)
{
    const int b0  = blockIdx.x * 2;
    const int tid = threadIdx.x;

    __shared__ float pl[2][NHID];

    if (tid < NHID) {
#pragma unroll
        for (int bb = 0; bb < 2; ++bb) {
            int count = lengths[b0 + bb]; if (count < 1) count = 1;
            const int nch = (count + CHUNK - 1) >> 6;
            float ssum = 0.f;
            for (int sp = 0; sp < nch; ++sp)
                ssum += partial[((size_t)sp * BB + (b0 + bb)) * NHID + tid];
            pl[bb][tid] = ssum / (float)count;
        }
    }
    __syncthreads();

    if (tid < 2 * NCOND) {
        const int bb = tid / NCOND;        // 0 or 1
        const int n  = tid - bb * NCOND;   // lanes 0..299 and 300..599 share Wa addrs
        const int b  = b0 + bb;
        float a0 = ba[n], a1 = 0.f, a2 = 0.f, a3 = 0.f;
        const float4* p4 = (const float4*)pl[bb];
        for (int h4 = 0; h4 < 148; h4 += 4) {   // h = 0..591
            const float4 pv0 = p4[h4];
            const float4 pv1 = p4[h4 + 1];
            const float4 pv2 = p4[h4 + 2];
            const float4 pv3 = p4[h4 + 3];
            const int hb = h4 * 4;
            a0 = fmaf(pv0.x, Wa[(size_t)(hb +  0) * NCOND + n], a0);
            a0 = fmaf(pv0.y, Wa[(size_t)(hb +  1) * NCOND + n], a0);
            a0 = fmaf(pv0.z, Wa[(size_t)(hb +  2) * NCOND + n], a0);
            a0 = fmaf(pv0.w, Wa[(size_t)(hb +  3) * NCOND + n], a0);
            a1 = fmaf(pv1.x, Wa[(size_t)(hb +  4) * NCOND + n], a1);
            a1 = fmaf(pv1.y, Wa[(size_t)(hb +  5) * NCOND + n], a1);
            a1 = fmaf(pv1.z, Wa[(size_t)(hb +  6) * NCOND + n], a1);
            a1 = fmaf(pv1.w, Wa[(size_t)(hb +  7) * NCOND + n], a1);
            a2 = fmaf(pv2.x, Wa[(size_t)(hb +  8) * NCOND + n], a2);
            a2 = fmaf(pv2.y, Wa[(size_t)(hb +  9) * NCOND + n], a2);
            a2 = fmaf(pv2.z, Wa[(size_t)(hb + 10) * NCOND + n], a2);
            a2 = fmaf(pv2.w, Wa[(size_t)(hb + 11) * NCOND + n], a2);
            a3 = fmaf(pv3.x, Wa[(size_t)(hb + 12) * NCOND + n], a3);
            a3 = fmaf(pv3.y, Wa[(size_t)(hb + 13) * NCOND + n], a3);
            a3 = fmaf(pv3.z, Wa[(size_t)(hb + 14) * NCOND + n], a3);
            a3 = fmaf(pv3.w, Wa[(size_t)(hb + 15) * NCOND + n], a3);
        }
        {   // tail: h = 592..599
            const float4 pv0 = p4[148];
            const float4 pv1 = p4[149];
            a0 = fmaf(pv0.x, Wa[(size_t)592 * NCOND + n], a0);
            a0 = fmaf(pv0.y, Wa[(size_t)593 * NCOND + n], a0);
            a0 = fmaf(pv0.z, Wa[(size_t)594 * NCOND + n], a0);
            a0 = fmaf(pv0.w, Wa[(size_t)595 * NCOND + n], a0);
            a1 = fmaf(pv1.x, Wa[(size_t)596 * NCOND + n], a1);
            a1 = fmaf(pv1.y, Wa[(size_t)597 * NCOND + n], a1);
            a1 = fmaf(pv1.z, Wa[(size_t)598 * NCOND + n], a1);
            a1 = fmaf(pv1.w, Wa[(size_t)599 * NCOND + n], a1);
        }
        const float acc  = (a0 + a1) + (a2 + a3);
        const float gate = 1.0f / (1.0f + expf(-acc));
        out[(size_t)b * NCOND + n] = gate * x[(size_t)b * NCOND + n];
    }
}

// ---------------------------------------------------------------------------
// Fallback path (ws too small for ctx16): exact round-0 kernel.
// ---------------------------------------------------------------------------
__global__ __launch_bounds__(256, 3) void k1_mfma_pool(
    const float* __restrict__ ctx, const int* __restrict__ lengths,
    const unsigned short* __restrict__ w1t, const float* __restrict__ b1,
    float* __restrict__ partial)
{
    const int b  = blockIdx.x;
    const int s  = blockIdx.y;
    const int ch = blockIdx.z;

    int count = lengths[b]; if (count < 1) count = 1;
    const int l0 = s * CHUNK;
    if (l0 >= count) return;
    const int valid = min(count - l0, CHUNK);

    const int tid  = threadIdx.x;
    const int lane = tid & 63;
    const int wv   = tid >> 6;
    const int ln15 = lane & 15;
    const int kg   = lane >> 4;

    __shared__ __align__(16) unsigned short atile[CHUNK * KLDS];

#pragma unroll
    for (int p = 0; p < 10; ++p) {
        const int i  = p * 256 + tid;
        const int r  = i / 40;
        const int c8 = i - r * 40;
        union { unsigned short us[8]; s16x8 v8; } u;
        if (r < valid && c8 < 38) {
            const float* src = ctx + ((size_t)b * LMAX + l0 + r) * NCOND + c8 * 8;
            const float4 v0 = *(const float4*)src;
            float4 v1 = make_float4(0.f, 0.f, 0.f, 0.f);
            if (c8 < 37) v1 = *(const float4*)(src + 4);
            u.us[0] = f2bf(v0.x); u.us[1] = f2bf(v0.y);
            u.us[2] = f2bf(v0.z); u.us[3] = f2bf(v0.w);
            u.us[4] = f2bf(v1.x); u.us[5] = f2bf(v1.y);
            u.us[6] = f2bf(v1.z); u.us[7] = f2bf(v1.w);
        } else {
#pragma unroll
            for (int j = 0; j < 8; ++j) u.us[j] = 0;
        }
        *(s16x8*)(atile + r * KLDS + c8 * 8) = u.v8;
    }
    __syncthreads();

    const int ntile0 = ch * 20 + wv * 5;
    const unsigned short* bbase = w1t + ((size_t)ntile0 * NKC * 64 + lane) * 8;
    const unsigned short* arow  = atile + ln15 * KLDS + kg * 8;

    f32x4 acc[5][4];
#pragma unroll
    for (int nt = 0; nt < 5; ++nt)
#pragma unroll
        for (int mt = 0; mt < 4; ++mt) acc[nt][mt] = (f32x4){0.f, 0.f, 0.f, 0.f};

    s16x8 bf[2][5];
#pragma unroll
    for (int nt = 0; nt < 5; ++nt) bf[0][nt] = *(const s16x8*)(bbase + nt * 5120);

#pragma unroll
    for (int kc = 0; kc < NKC; ++kc) {
        const int cur = kc & 1, nxt = cur ^ 1;
        if (kc < NKC - 1) {
#pragma unroll
            for (int nt = 0; nt < 5; ++nt)
                bf[nxt][nt] = *(const s16x8*)(bbase + nt * 5120 + (kc + 1) * 512);
        }
        s16x8 af[4];
#pragma unroll
        for (int mt = 0; mt < 4; ++mt)
            af[mt] = *(const s16x8*)(arow + mt * 16 * KLDS + kc * 32);
#pragma unroll
        for (int nt = 0; nt < 5; ++nt)
#pragma unroll
            for (int mt = 0; mt < 4; ++mt)
                acc[nt][mt] = __builtin_amdgcn_mfma_f32_16x16x32_bf16(
                    af[mt], bf[cur][nt], acc[nt][mt], 0, 0, 0);
    }

#pragma unroll
    for (int nt = 0; nt < 5; ++nt) {
        const int colg = ch * 320 + wv * 80 + nt * 16 + ln15;
        const float b1c = (colg < NHID) ? b1[colg] : 0.f;
        float ssum = 0.f;
#pragma unroll
        for (int mt = 0; mt < 4; ++mt) {
            const int rbase = mt * 16 + kg * 4;
#pragma unroll
            for (int r = 0; r < 4; ++r) {
                const float h = fmaxf(acc[nt][mt][r] + b1c, 0.f);
                if (rbase + r < valid) ssum += h;
            }
        }
        ssum += __shfl_xor(ssum, 16, 64);
        ssum += __shfl_xor(ssum, 32, 64);
        if (kg == 0 && colg < NHID)
            partial[((size_t)s * BB + b) * NHID + colg] = ssum;
    }
}

extern "C" void kernel_launch(void* const* d_in, const int* in_sizes, int n_in,
                              void* d_out, int out_size, void* d_ws, size_t ws_size,
                              hipStream_t stream)
{
    // setup_inputs() order: x, context, lengths, W1, b1, Wa, ba
    const float* x       = (const float*)d_in[0];
    const float* ctx     = (const float*)d_in[1];
    const int*   lengths = (const int*)  d_in[2];
    const float* W1      = (const float*)d_in[3];
    const float* b1      = (const float*)d_in[4];
    const float* Wa      = (const float*)d_in[5];
    const float* ba      = (const float*)d_in[6];
    float*       out     = (float*)d_out;

    // ws layout: [w1t 409,600][partial 4,915,200][ctx16 row-swz 83,886,080]
    const size_t W1T_B   = 409600;
    const size_t PART_B  = 4915200;                         // [8][256][600] f32
    const size_t CTX16_B = (size_t)BB * LMAX * KPAD * 2;    // 83,886,080
    const size_t NEED    = W1T_B + PART_B + CTX16_B;

    unsigned short* w1t     = (unsigned short*)d_ws;
    float*          partial = (float*)((char*)d_ws + W1T_B);

    k0_w1t<<<100, 256, 0, stream>>>(W1, w1t);

    if (ws_size >= NEED) {
        unsigned short* ctx16 = (unsigned short*)((char*)d_ws + W1T_B + PART_B);
        k0b_cvt<<<dim3(BB, NSEG), 256, 0, stream>>>(ctx, lengths, ctx16);
        k1_dma2<<<dim3(BB, NSEG, 2), 512, 0, stream>>>(ctx16, lengths, w1t, b1, partial);
    } else {
        k1_mfma_pool<<<dim3(BB, NSEG, 2), 256, 0, stream>>>(ctx, lengths, w1t, b1, partial);
    }

    k2_gate<<<BB / 2, 640, 0, stream>>>(x, lengths, partial, Wa, ba, out);
}

// Round 8
// 291.334 us; speedup vs baseline: 2.8116x; 1.1116x over previous
//
#include <hip/hip_runtime.h>
#include <math.h>

// Problem constants: B=256, LMAX=512, NCOND=300, NHID=600
#define BB     256
#define LMAX   512
#define NCOND  300
#define NHID   600
#define NSEG   8          // 8 segments of 64 tokens; block = one segment chunk
#define CHUNK  64
#define KPAD   320        // K padded to 10 chunks of 32 (k>=300 zero in W1T)
#define KLDS   328        // LDS row stride (elems): 656 B, 16B-aligned, 2-way bank alias = free
#define NKC    10         // KPAD/32

typedef short s16x8 __attribute__((ext_vector_type(8)));  // MFMA A/B frag (8 bf16)
typedef float f32x4 __attribute__((ext_vector_type(4)));  // MFMA accumulator

// fp32 -> bf16 round-to-nearest-even
__device__ inline unsigned short f2bf(float f) {
    unsigned int x = __float_as_uint(f);
    x += 0x7fffu + ((x >> 16) & 1u);
    return (unsigned short)(x >> 16);
}

// ---------------------------------------------------------------------------
// k0: build W1T bf16 in FRAGMENT-MAJOR layout (round-0 proven):
//   w1t[((ntile*NKC + kc)*64 + lane)*8 + j] = W1[kc*32+(lane>>4)*8+j][ntile*16+(lane&15)]
// -> a wave's B-frag load is one contiguous 1 KB global_load_dwordx4.
// ---------------------------------------------------------------------------
__global__ __launch_bounds__(256) void k0_w1t(const float* __restrict__ W1,
                                              unsigned short* __restrict__ w1t)
{
    const int t     = blockIdx.x * 256 + threadIdx.x;  // 0..25599
    const int lane  = t & 63;
    const int g     = t >> 6;                          // ntile*NKC + kc
    const int ntile = g / NKC;
    const int kc    = g - ntile * NKC;
    const int n     = ntile * 16 + (lane & 15);
    const int kbase = kc * 32 + (lane >> 4) * 8;
    union { unsigned short us[8]; s16x8 v8; } u;
#pragma unroll
    for (int j = 0; j < 8; ++j) {
        const int k = kbase + j;
        const float w = (n < NHID && k < NCOND) ? W1[(size_t)k * NHID + n] : 0.f;
        u.us[j] = f2bf(w);
    }
    *(s16x8*)(w1t + (size_t)t * 8) = u.v8;
}

// ---------------------------------------------------------------------------
// k1_mfma_pool: EXACT round-0 body (95.6 us anchor) with ONE change: grid is
//   1-D (4096) and decomposed as
//       wg = b*16 + ch*8 + j,   s = (j + b) & 7
//   so that:
//   - the ch=0 / ch=1 blocks that stage the SAME 76.8 KB ctx tile are exactly
//     8 dispatch indices apart -> same XCD under the round-robin wg->XCD
//     mapping -> the second block's 20 staging loads hit that XCD's L2
//     (in round 0 the pair was 2048 dispatches apart: L3-dedup only);
//   - s is rotated by b so dead segments spread evenly across XCDs
//     (without rotation XCD j would own segment j of every batch: XCD 0
//     always live, XCD 7 ~95% dead).
//   Mapping affects locality only, never correctness (G16-safe).
// ---------------------------------------------------------------------------
__global__ __launch_bounds__(256, 3) void k1_mfma_pool(
    const float* __restrict__ ctx, const int* __restrict__ lengths,
    const unsigned short* __restrict__ w1t, const float* __restrict__ b1,
    float* __restrict__ partial)
{
    const int wg = blockIdx.x;              // 0..4095
    const int b  = wg >> 4;                 // batch
    const int ch = (wg >> 3) & 1;           // col-half
    const int s  = ((wg & 7) + b) & 7;      // rotated segment

    int count = lengths[b]; if (count < 1) count = 1;   // reference clamps lens >= 1
    const int l0 = s * CHUNK;
    if (l0 >= count) return;                            // empty segment: no work, no write
    const int valid = min(count - l0, CHUNK);

    const int tid  = threadIdx.x;
    const int lane = tid & 63;
    const int wv   = tid >> 6;
    const int ln15 = lane & 15;
    const int kg   = lane >> 4;

    __shared__ __align__(16) unsigned short atile[CHUNK * KLDS];   // 41,984 B

    // ---- stage 64 x KPAD bf16; rows >= valid and k >= 300 zero-filled.
#pragma unroll
    for (int p = 0; p < 10; ++p) {
        const int i  = p * 256 + tid;          // 0..2559
        const int r  = i / 40;
        const int c8 = i - r * 40;             // 8-elem column chunk
        union { unsigned short us[8]; s16x8 v8; } u;
        if (r < valid && c8 < 38) {
            const float* src = ctx + ((size_t)b * LMAX + l0 + r) * NCOND + c8 * 8;
            const float4 v0 = *(const float4*)src;
            float4 v1 = make_float4(0.f, 0.f, 0.f, 0.f);
            if (c8 < 37) v1 = *(const float4*)(src + 4);
            u.us[0] = f2bf(v0.x); u.us[1] = f2bf(v0.y);
            u.us[2] = f2bf(v0.z); u.us[3] = f2bf(v0.w);
            u.us[4] = f2bf(v1.x); u.us[5] = f2bf(v1.y);
            u.us[6] = f2bf(v1.z); u.us[7] = f2bf(v1.w);
        } else {
#pragma unroll
            for (int j = 0; j < 8; ++j) u.us[j] = 0;
        }
        *(s16x8*)(atile + r * KLDS + c8 * 8) = u.v8;
    }
    __syncthreads();

    // ---- MFMA: wave wv owns cols [ch*320 + wv*80, +80) = 5 n-tiles x 4 m-tiles
    const int ntile0 = ch * 20 + wv * 5;
    const unsigned short* bbase = w1t + ((size_t)ntile0 * NKC * 64 + lane) * 8;
    const unsigned short* arow  = atile + ln15 * KLDS + kg * 8;

    f32x4 acc[5][4];
#pragma unroll
    for (int nt = 0; nt < 5; ++nt)
#pragma unroll
        for (int mt = 0; mt < 4; ++mt) acc[nt][mt] = (f32x4){0.f, 0.f, 0.f, 0.f};

    s16x8 bf[2][5];
#pragma unroll
    for (int nt = 0; nt < 5; ++nt) bf[0][nt] = *(const s16x8*)(bbase + nt * 5120);

#pragma unroll
    for (int kc = 0; kc < NKC; ++kc) {
        const int cur = kc & 1, nxt = cur ^ 1;
        if (kc < NKC - 1) {
#pragma unroll
            for (int nt = 0; nt < 5; ++nt)
                bf[nxt][nt] = *(const s16x8*)(bbase + nt * 5120 + (kc + 1) * 512);
        }
        s16x8 af[4];
#pragma unroll
        for (int mt = 0; mt < 4; ++mt)
            af[mt] = *(const s16x8*)(arow + mt * 16 * KLDS + kc * 32);
#pragma unroll
        for (int nt = 0; nt < 5; ++nt)
#pragma unroll
            for (int mt = 0; mt < 4; ++mt)
                acc[nt][mt] = __builtin_amdgcn_mfma_f32_16x16x32_bf16(
                    af[mt], bf[cur][nt], acc[nt][mt], 0, 0, 0);
    }

    // ---- epilogue: bias + ReLU, mask rows >= valid, reduce k-groups, write
#pragma unroll
    for (int nt = 0; nt < 5; ++nt) {
        const int colg = ch * 320 + wv * 80 + nt * 16 + ln15;
        const float b1c = (colg < NHID) ? b1[colg] : 0.f;
        float ssum = 0.f;
#pragma unroll
        for (int mt = 0; mt < 4; ++mt) {
            const int rbase = mt * 16 + kg * 4;
#pragma unroll
            for (int r = 0; r < 4; ++r) {
                const float h = fmaxf(acc[nt][mt][r] + b1c, 0.f);
                if (rbase + r < valid) ssum += h;
            }
        }
        ssum += __shfl_xor(ssum, 16, 64);
        ssum += __shfl_xor(ssum, 32, 64);
        if (kg == 0 && colg < NHID)
            partial[((size_t)s * BB + b) * NHID + colg] = ssum;
    }
}

// ---------------------------------------------------------------------------
// k2: 2 batches per block (same-n lanes share Wa loads). Reduce partials over
//     sp < ceil(len/64) (others unwritten/poisoned -> skipped), /len, then
//     gate = sigmoid(pooled@Wa + ba); out = gate * x.   (round-0 proven)
// NOTE: NHID/4 = 150 float4s = 37*4 + 2 -> 4-wide main loop to h4<148, then
//       a 2-float4 tail.
// ---------------------------------------------------------------------------
__global__ __launch_bounds__(640) void k2_gate(
    const float* __restrict__ x, const int* __restrict__ lengths,
    const float* __restrict__ partial, const float* __restrict__ Wa,
    const float* __restrict__ ba, float* __restrict__ out)
{
    const int b0  = blockIdx.x * 2;
    const int tid = threadIdx.x;

    __shared__ float pl[2][NHID];

    if (tid < NHID) {
#pragma unroll
        for (int bb = 0; bb < 2; ++bb) {
            int count = lengths[b0 + bb]; if (count < 1) count = 1;
            const int nch = (count + CHUNK - 1) >> 6;
            float ssum = 0.f;
            for (int sp = 0; sp < nch; ++sp)
                ssum += partial[((size_t)sp * BB + (b0 + bb)) * NHID + tid];
            pl[bb][tid] = ssum / (float)count;
        }
    }
    __syncthreads();

    if (tid < 2 * NCOND) {
        const int bb = tid / NCOND;        // 0 or 1
        const int n  = tid - bb * NCOND;   // lanes 0..299 and 300..599 share Wa addrs
        const int b  = b0 + bb;
        float a0 = ba[n], a1 = 0.f, a2 = 0.f, a3 = 0.f;
        const float4* p4 = (const float4*)pl[bb];
        for (int h4 = 0; h4 < 148; h4 += 4) {   // h = 0..591
            const float4 pv0 = p4[h4];
            const float4 pv1 = p4[h4 + 1];
            const float4 pv2 = p4[h4 + 2];
            const float4 pv3 = p4[h4 + 3];
            const int hb = h4 * 4;
            a0 = fmaf(pv0.x, Wa[(size_t)(hb +  0) * NCOND + n], a0);
            a0 = fmaf(pv0.y, Wa[(size_t)(hb +  1) * NCOND + n], a0);
            a0 = fmaf(pv0.z, Wa[(size_t)(hb +  2) * NCOND + n], a0);
            a0 = fmaf(pv0.w, Wa[(size_t)(hb +  3) * NCOND + n], a0);
            a1 = fmaf(pv1.x, Wa[(size_t)(hb +  4) * NCOND + n], a1);
            a1 = fmaf(pv1.y, Wa[(size_t)(hb +  5) * NCOND + n], a1);
            a1 = fmaf(pv1.z, Wa[(size_t)(hb +  6) * NCOND + n], a1);
            a1 = fmaf(pv1.w, Wa[(size_t)(hb +  7) * NCOND + n], a1);
            a2 = fmaf(pv2.x, Wa[(size_t)(hb +  8) * NCOND + n], a2);
            a2 = fmaf(pv2.y, Wa[(size_t)(hb +  9) * NCOND + n], a2);
            a2 = fmaf(pv2.z, Wa[(size_t)(hb + 10) * NCOND + n], a2);
            a2 = fmaf(pv2.w, Wa[(size_t)(hb + 11) * NCOND + n], a2);
            a3 = fmaf(pv3.x, Wa[(size_t)(hb + 12) * NCOND + n], a3);
            a3 = fmaf(pv3.y, Wa[(size_t)(hb + 13) * NCOND + n], a3);
            a3 = fmaf(pv3.z, Wa[(size_t)(hb + 14) * NCOND + n], a3);
            a3 = fmaf(pv3.w, Wa[(size_t)(hb + 15) * NCOND + n], a3);
        }
        {   // tail: h = 592..599
            const float4 pv0 = p4[148];
            const float4 pv1 = p4[149];
            a0 = fmaf(pv0.x, Wa[(size_t)592 * NCOND + n], a0);
            a0 = fmaf(pv0.y, Wa[(size_t)593 * NCOND + n], a0);
            a0 = fmaf(pv0.z, Wa[(size_t)594 * NCOND + n], a0);
            a0 = fmaf(pv0.w, Wa[(size_t)595 * NCOND + n], a0);
            a1 = fmaf(pv1.x, Wa[(size_t)596 * NCOND + n], a1);
            a1 = fmaf(pv1.y, Wa[(size_t)597 * NCOND + n], a1);
            a1 = fmaf(pv1.z, Wa[(size_t)598 * NCOND + n], a1);
            a1 = fmaf(pv1.w, Wa[(size_t)599 * NCOND + n], a1);
        }
        const float acc  = (a0 + a1) + (a2 + a3);
        const float gate = 1.0f / (1.0f + expf(-acc));
        out[(size_t)b * NCOND + n] = gate * x[(size_t)b * NCOND + n];
    }
}

extern "C" void kernel_launch(void* const* d_in, const int* in_sizes, int n_in,
                              void* d_out, int out_size, void* d_ws, size_t ws_size,
                              hipStream_t stream)
{
    // setup_inputs() order: x, context, lengths, W1, b1, Wa, ba
    const float* x       = (const float*)d_in[0];
    const float* ctx     = (const float*)d_in[1];
    const int*   lengths = (const int*)  d_in[2];
    const float* W1      = (const float*)d_in[3];
    const float* b1      = (const float*)d_in[4];
    const float* Wa      = (const float*)d_in[5];
    const float* ba      = (const float*)d_in[6];
    float*       out     = (float*)d_out;

    // ws layout: [w1t frag-major bf16: 409,600 B][partial fp32 8*256*600: 4,915,200 B]
    unsigned short* w1t     = (unsigned short*)d_ws;
    float*          partial = (float*)((char*)d_ws + 409600);

    k0_w1t<<<100, 256, 0, stream>>>(W1, w1t);
    k1_mfma_pool<<<BB * NSEG * 2, 256, 0, stream>>>(ctx, lengths, w1t, b1, partial);
    k2_gate<<<BB / 2, 640, 0, stream>>>(x, lengths, partial, Wa, ba, out);
}

// Round 9
// 290.147 us; speedup vs baseline: 2.8231x; 1.0041x over previous
//
#include <hip/hip_runtime.h>
#include <math.h>

// Problem constants: B=256, LMAX=512, NCOND=300, NHID=600
#define BB     256
#define LMAX   512
#define NCOND  300
#define NHID   600
#define NSEG   8          // 8 segments of 64 tokens
#define CHUNK  64
#define KPAD   320        // K padded to 10 chunks of 32 (k>=300 zero in W1T)
#define KLDS   328        // LDS row stride (elems): 656 B, 16B-aligned, 2-way bank alias = free
#define NKC    10         // KPAD/32

typedef short s16x8 __attribute__((ext_vector_type(8)));  // MFMA A/B frag (8 bf16)
typedef float f32x4 __attribute__((ext_vector_type(4)));  // MFMA accumulator

// fp32 -> bf16 round-to-nearest-even
__device__ inline unsigned short f2bf(float f) {
    unsigned int x = __float_as_uint(f);
    x += 0x7fffu + ((x >> 16) & 1u);
    return (unsigned short)(x >> 16);
}

// ---------------------------------------------------------------------------
// k0: build W1T bf16 in FRAGMENT-MAJOR layout (round-0 proven):
//   w1t[((ntile*NKC + kc)*64 + lane)*8 + j] = W1[kc*32+(lane>>4)*8+j][ntile*16+(lane&15)]
// ---------------------------------------------------------------------------
__global__ __launch_bounds__(256) void k0_w1t(const float* __restrict__ W1,
                                              unsigned short* __restrict__ w1t)
{
    const int t     = blockIdx.x * 256 + threadIdx.x;  // 0..25599
    const int lane  = t & 63;
    const int g     = t >> 6;                          // ntile*NKC + kc
    const int ntile = g / NKC;
    const int kc    = g - ntile * NKC;
    const int n     = ntile * 16 + (lane & 15);
    const int kbase = kc * 32 + (lane >> 4) * 8;
    union { unsigned short us[8]; s16x8 v8; } u;
#pragma unroll
    for (int j = 0; j < 8; ++j) {
        const int k = kbase + j;
        const float w = (n < NHID && k < NCOND) ? W1[(size_t)k * NHID + n] : 0.f;
        u.us[j] = f2bf(w);
    }
    *(s16x8*)(w1t + (size_t)t * 8) = u.v8;
}

// ---------------------------------------------------------------------------
// k1_mfma_mh: r8's verified body with the m-dimension split in half to break
//   the 3-blocks/CU register cap.
//   Block = (b, s, ch, mh): 256 thr / 4 waves; wave = 5 n-tiles x 2 m-tiles
//   over a 32-row LDS tile (20,992 B). Regs: bf 40 + af 8 + addr ~28 VGPR
//   + acc[5][2] = 40 AGPR => ~116 < 128 -> __launch_bounds__(256,4):
//   4 blocks/CU, 16 waves/CU (vs 12). Per-block staging & MFMA halve.
//   Grid 1-D 8192:  wg = b*32 + mh*16 + ch*8 + j,  s = (j+b)&7
//   -> ch-pair (same rows) 8 apart = same XCD (r8-verified win);
//   -> s rotated by b spreads dead segments across XCDs.
//   mh halves write DISJOINT partial planes (no atomics on poisoned ws);
//   k2 sums both planes. mh=1 with valid<=32 writes zeros (k2 still reads it).
// ---------------------------------------------------------------------------
__global__ __launch_bounds__(256, 4) void k1_mfma_mh(
    const float* __restrict__ ctx, const int* __restrict__ lengths,
    const unsigned short* __restrict__ w1t, const float* __restrict__ b1,
    float* __restrict__ partial)   // two planes of [NSEG][BB][NHID]
{
    const int wg = blockIdx.x;              // 0..8191
    const int b  = wg >> 5;                 // batch
    const int mh = (wg >> 4) & 1;           // m-half: rows [mh*32, mh*32+32)
    const int ch = (wg >> 3) & 1;           // col-half
    const int s  = ((wg & 7) + b) & 7;      // rotated segment

    int count = lengths[b]; if (count < 1) count = 1;   // reference clamps lens >= 1
    const int l0 = s * CHUNK;
    if (l0 >= count) return;                            // dead segment: neither plane read
    const int valid = min(count - l0, CHUNK);           // rows of the FULL 64-row segment

    const int tid  = threadIdx.x;
    const int lane = tid & 63;
    const int wv   = tid >> 6;
    const int ln15 = lane & 15;
    const int kg   = lane >> 4;

    __shared__ __align__(16) unsigned short atile[32 * KLDS];   // 20,992 B

    // ---- stage 32 x KPAD bf16 (rows mh*32 .. mh*32+31); rows >= valid and
    //      k >= 300 zero-filled. 1280 chunks / 256 threads = 5 iters exact.
#pragma unroll
    for (int p = 0; p < 5; ++p) {
        const int i  = p * 256 + tid;          // 0..1279
        const int r  = i / 40;                 // local row 0..31
        const int c8 = i - r * 40;             // 8-elem column chunk
        const int rg = mh * 32 + r;            // global row in segment
        union { unsigned short us[8]; s16x8 v8; } u;
        if (rg < valid && c8 < 38) {
            const float* src = ctx + ((size_t)b * LMAX + l0 + rg) * NCOND + c8 * 8;
            const float4 v0 = *(const float4*)src;
            float4 v1 = make_float4(0.f, 0.f, 0.f, 0.f);
            if (c8 < 37) v1 = *(const float4*)(src + 4);
            u.us[0] = f2bf(v0.x); u.us[1] = f2bf(v0.y);
            u.us[2] = f2bf(v0.z); u.us[3] = f2bf(v0.w);
            u.us[4] = f2bf(v1.x); u.us[5] = f2bf(v1.y);
            u.us[6] = f2bf(v1.z); u.us[7] = f2bf(v1.w);
        } else {
#pragma unroll
            for (int j = 0; j < 8; ++j) u.us[j] = 0;
        }
        *(s16x8*)(atile + r * KLDS + c8 * 8) = u.v8;
    }
    __syncthreads();

    // ---- MFMA: wave wv owns cols [ch*320 + wv*80, +80) = 5 n-tiles x 2 m-tiles
    const int ntile0 = ch * 20 + wv * 5;
    const unsigned short* bbase = w1t + ((size_t)ntile0 * NKC * 64 + lane) * 8;
    const unsigned short* arow  = atile + ln15 * KLDS + kg * 8;

    f32x4 acc[5][2];
#pragma unroll
    for (int nt = 0; nt < 5; ++nt) {
        acc[nt][0] = (f32x4){0.f, 0.f, 0.f, 0.f};
        acc[nt][1] = (f32x4){0.f, 0.f, 0.f, 0.f};
    }

    s16x8 bf[2][5];
#pragma unroll
    for (int nt = 0; nt < 5; ++nt) bf[0][nt] = *(const s16x8*)(bbase + nt * 5120);

#pragma unroll
    for (int kc = 0; kc < NKC; ++kc) {
        const int cur = kc & 1, nxt = cur ^ 1;
        if (kc < NKC - 1) {
#pragma unroll
            for (int nt = 0; nt < 5; ++nt)
                bf[nxt][nt] = *(const s16x8*)(bbase + nt * 5120 + (kc + 1) * 512);
        }
        s16x8 af[2];
        af[0] = *(const s16x8*)(arow + kc * 32);
        af[1] = *(const s16x8*)(arow + 16 * KLDS + kc * 32);
#pragma unroll
        for (int nt = 0; nt < 5; ++nt) {
            acc[nt][0] = __builtin_amdgcn_mfma_f32_16x16x32_bf16(
                af[0], bf[cur][nt], acc[nt][0], 0, 0, 0);
            acc[nt][1] = __builtin_amdgcn_mfma_f32_16x16x32_bf16(
                af[1], bf[cur][nt], acc[nt][1], 0, 0, 0);
        }
    }

    // ---- epilogue: bias + ReLU, mask rows >= valid, reduce kg, write plane[mh]
    float* plane = partial + (size_t)mh * (NSEG * BB * NHID);
#pragma unroll
    for (int nt = 0; nt < 5; ++nt) {
        const int colg = ch * 320 + wv * 80 + nt * 16 + ln15;
        const float b1c = (colg < NHID) ? b1[colg] : 0.f;
        float ssum = 0.f;
#pragma unroll
        for (int j = 0; j < 2; ++j) {
            const int rbase = (mh * 2 + j) * 16 + kg * 4;   // global row base
#pragma unroll
            for (int r = 0; r < 4; ++r) {
                const float h = fmaxf(acc[nt][j][r] + b1c, 0.f);
                if (rbase + r < valid) ssum += h;
            }
        }
        ssum += __shfl_xor(ssum, 16, 64);
        ssum += __shfl_xor(ssum, 32, 64);
        if (kg == 0 && colg < NHID)
            plane[((size_t)s * BB + b) * NHID + colg] = ssum;
    }
}

// ---------------------------------------------------------------------------
// k2: 2 batches per block. Reduce BOTH mh planes over sp < ceil(len/64)
//     (others unwritten/poisoned -> skipped), /len, then
//     gate = sigmoid(pooled@Wa + ba); out = gate * x.
// ---------------------------------------------------------------------------
__global__ __launch_bounds__(640) void k2_gate(
    const float* __restrict__ x, const int* __restrict__ lengths,
    const float* __restrict__ partial, const float* __restrict__ Wa,
    const float* __restrict__ ba, float* __restrict__ out)
{
    const int b0  = blockIdx.x * 2;
    const int tid = threadIdx.x;

    __shared__ float pl[2][NHID];

    const float* plane1 = partial + (size_t)NSEG * BB * NHID;

    if (tid < NHID) {
#pragma unroll
        for (int bb = 0; bb < 2; ++bb) {
            int count = lengths[b0 + bb]; if (count < 1) count = 1;
            const int nch = (count + CHUNK - 1) >> 6;
            float ssum = 0.f;
            for (int sp = 0; sp < nch; ++sp) {
                const size_t off = ((size_t)sp * BB + (b0 + bb)) * NHID + tid;
                ssum += partial[off] + plane1[off];
            }
            pl[bb][tid] = ssum / (float)count;
        }
    }
    __syncthreads();

    if (tid < 2 * NCOND) {
        const int bb = tid / NCOND;        // 0 or 1
        const int n  = tid - bb * NCOND;   // lanes 0..299 and 300..599 share Wa addrs
        const int b  = b0 + bb;
        float a0 = ba[n], a1 = 0.f, a2 = 0.f, a3 = 0.f;
        const float4* p4 = (const float4*)pl[bb];
        for (int h4 = 0; h4 < 148; h4 += 4) {   // h = 0..591
            const float4 pv0 = p4[h4];
            const float4 pv1 = p4[h4 + 1];
            const float4 pv2 = p4[h4 + 2];
            const float4 pv3 = p4[h4 + 3];
            const int hb = h4 * 4;
            a0 = fmaf(pv0.x, Wa[(size_t)(hb +  0) * NCOND + n], a0);
            a0 = fmaf(pv0.y, Wa[(size_t)(hb +  1) * NCOND + n], a0);
            a0 = fmaf(pv0.z, Wa[(size_t)(hb +  2) * NCOND + n], a0);
            a0 = fmaf(pv0.w, Wa[(size_t)(hb +  3) * NCOND + n], a0);
            a1 = fmaf(pv1.x, Wa[(size_t)(hb +  4) * NCOND + n], a1);
            a1 = fmaf(pv1.y, Wa[(size_t)(hb +  5) * NCOND + n], a1);
            a1 = fmaf(pv1.z, Wa[(size_t)(hb +  6) * NCOND + n], a1);
            a1 = fmaf(pv1.w, Wa[(size_t)(hb +  7) * NCOND + n], a1);
            a2 = fmaf(pv2.x, Wa[(size_t)(hb +  8) * NCOND + n], a2);
            a2 = fmaf(pv2.y, Wa[(size_t)(hb +  9) * NCOND + n], a2);
            a2 = fmaf(pv2.z, Wa[(size_t)(hb + 10) * NCOND + n], a2);
            a2 = fmaf(pv2.w, Wa[(size_t)(hb + 11) * NCOND + n], a2);
            a3 = fmaf(pv3.x, Wa[(size_t)(hb + 12) * NCOND + n], a3);
            a3 = fmaf(pv3.y, Wa[(size_t)(hb + 13) * NCOND + n], a3);
            a3 = fmaf(pv3.z, Wa[(size_t)(hb + 14) * NCOND + n], a3);
            a3 = fmaf(pv3.w, Wa[(size_t)(hb + 15) * NCOND + n], a3);
        }
        {   // tail: h = 592..599
            const float4 pv0 = p4[148];
            const float4 pv1 = p4[149];
            a0 = fmaf(pv0.x, Wa[(size_t)592 * NCOND + n], a0);
            a0 = fmaf(pv0.y, Wa[(size_t)593 * NCOND + n], a0);
            a0 = fmaf(pv0.z, Wa[(size_t)594 * NCOND + n], a0);
            a0 = fmaf(pv0.w, Wa[(size_t)595 * NCOND + n], a0);
            a1 = fmaf(pv1.x, Wa[(size_t)596 * NCOND + n], a1);
            a1 = fmaf(pv1.y, Wa[(size_t)597 * NCOND + n], a1);
            a1 = fmaf(pv1.z, Wa[(size_t)598 * NCOND + n], a1);
            a1 = fmaf(pv1.w, Wa[(size_t)599 * NCOND + n], a1);
        }
        const float acc  = (a0 + a1) + (a2 + a3);
        const float gate = 1.0f / (1.0f + expf(-acc));
        out[(size_t)b * NCOND + n] = gate * x[(size_t)b * NCOND + n];
    }
}

extern "C" void kernel_launch(void* const* d_in, const int* in_sizes, int n_in,
                              void* d_out, int out_size, void* d_ws, size_t ws_size,
                              hipStream_t stream)
{
    // setup_inputs() order: x, context, lengths, W1, b1, Wa, ba
    const float* x       = (const float*)d_in[0];
    const float* ctx     = (const float*)d_in[1];
    const int*   lengths = (const int*)  d_in[2];
    const float* W1      = (const float*)d_in[3];
    const float* b1      = (const float*)d_in[4];
    const float* Wa      = (const float*)d_in[5];
    const float* ba      = (const float*)d_in[6];
    float*       out     = (float*)d_out;

    // ws layout: [w1t 409,600 B][partial 2 planes x 4,915,200 B]
    unsigned short* w1t     = (unsigned short*)d_ws;
    float*          partial = (float*)((char*)d_ws + 409600);

    k0_w1t<<<100, 256, 0, stream>>>(W1, w1t);
    k1_mfma_mh<<<BB * NSEG * 4, 256, 0, stream>>>(ctx, lengths, w1t, b1, partial);
    k2_gate<<<BB / 2, 640, 0, stream>>>(x, lengths, partial, Wa, ba, out);
}